// Round 12
// baseline (24.083 us; speedup 1.0000x reference)
//
#include <hip/hip_runtime.h>
#include <hip/hip_fp16.h>

typedef _Float16 half8 __attribute__((ext_vector_type(8)));
typedef _Float16 half2v __attribute__((ext_vector_type(2)));
typedef float f32x2 __attribute__((ext_vector_type(2)));
typedef float f32x4 __attribute__((ext_vector_type(4)));

__device__ __forceinline__ float leakyf(float v) { return v >= 0.f ? v : 0.7f * v; }

// R11 structure exactly, plus ONE change: the first tile's inputs (tgt row,
// deg1/deg2 gathers, all 16 f-row loads) are issued BEFORE the weight-staging
// phase, into a statically-indexed register array. Their ~2 serial HBM
// round-trips overlap the staging loads instead of following the barrier.
__global__ __launch_bounds__(512, 4)
void shgnn_fused6(const float* __restrict__ f0, const float* __restrict__ f1,
                  const float* __restrict__ f2, const float* __restrict__ W,
                  const float* __restrict__ b, const float* __restrict__ Wc,
                  const float* __restrict__ bc, const float* __restrict__ Wout,
                  const float* __restrict__ bout,
                  const int* __restrict__ tgt, const int* __restrict__ deg1,
                  const int* __restrict__ deg2,
                  int T, int per_type,
                  float* __restrict__ out_logits, float* __restrict__ out_h)
{
    __shared__ _Float16 sWF[24 * 512];   // 24KB: stacked-W B-frags [ks=0..5][n=0..3]
    __shared__ _Float16 sOF[16 * 512];   // 16KB: Wout B-frags [ks=0..3][n=0..3]
    __shared__ _Float16 sX[8][2048];     // 32KB: per-wave [row=16][ch=128] swizzled
    __shared__ float sB[192];
    __shared__ float sBC[192];
    __shared__ float sBout[64];

    const int tid = threadIdx.x;
    const int lane = tid & 63;
    const int l15 = lane & 15;
    const int lq  = lane >> 4;
    const int wid = tid >> 6;
    char* const sXw = (char*)sX[wid];

    const int ntiles = (T + 15) >> 4;

    // balanced contiguous chunk per block
    const int nb = gridDim.x;
    const int q = ntiles / nb, rr = ntiles % nb;
    const int cstart = blockIdx.x * q + (blockIdx.x < rr ? blockIdx.x : rr);
    const int cend   = cstart + q + (blockIdx.x < rr ? 1 : 0);
    const int tile0  = cstart + wid;

    // ---- hoisted first-tile input loads (overlap the staging below) ----
    int nnv = 0, d1v = 0, d2v = 0;
    float fvr[16];
    if (tile0 < cend) {
        int t = tile0 * 16 + l15;
        if (t >= T) t = T - 1;
        nnv = tgt[t];                                 // coalesced 64B
        d1v = deg1[nnv];                              // per-lane gathers
        d2v = deg2[nnv];
        #pragma unroll
        for (int r = 0; r < 16; ++r) {
            const int nr  = __builtin_amdgcn_readlane(nnv, r);
            const int tyr = (nr >= 2 * per_type) ? 2 : (nr >= per_type ? 1 : 0);
            const float* fbr = (tyr == 0) ? f0 : ((tyr == 1) ? f1 : f2);
            fvr[r] = fbr[(size_t)(nr - tyr * per_type) * 64 + lane];
        }
    }

    // ---- stage weight fragments (coalesced fp32 reads, scattered b16 writes) ----
    for (int i = tid; i < 3 * 64 * 64; i += 512) {         // i = K*64 + col, K=ty*64+k
        const int K = i >> 6, col = i & 63;
        const int ks = K >> 5, j = K & 7;
        const int ln = (((K >> 3) & 3) << 4) | (col & 15);
        const int n = col >> 4;
        sWF[((ks * 4 + n) << 9) + (ln << 3) + j] = (_Float16)W[i];
    }
    for (int i = tid; i < 128 * 64; i += 512) {            // i = k*64 + col
        const int k = i >> 6, col = i & 63;
        const int ks = k >> 5, j = k & 7;
        const int ln = (((k >> 3) & 3) << 4) | (col & 15);
        const int n = col >> 4;
        sOF[((ks * 4 + n) << 9) + (ln << 3) + j] = (_Float16)Wout[i];
    }
    if (tid < 192) sB[tid] = b[tid];
    if (tid < 192) sBC[tid] = bc[tid];
    if (tid < 64)  sBout[tid] = bout[tid];
    __syncthreads();

    for (int tile = tile0; tile < cend; tile += 8) {
        if (tile != tile0) {                          // cold path (unused at T=50000)
            int t = tile * 16 + l15;
            if (t >= T) t = T - 1;
            nnv = tgt[t];
            d1v = deg1[nnv];
            d2v = deg2[nnv];
            #pragma unroll
            for (int r = 0; r < 16; ++r) {
                const int nr  = __builtin_amdgcn_readlane(nnv, r);
                const int tyr = (nr >= 2 * per_type) ? 2 : (nr >= per_type ? 1 : 0);
                const float* fbr = (tyr == 0) ? f0 : ((tyr == 1) ? f1 : f2);
                fvr[r] = fbr[(size_t)(nr - tyr * per_type) * 64 + lane];
            }
        }
        const int tyv = (nnv >= 2 * per_type) ? 2 : (nnv >= per_type ? 1 : 0);

        // ---- phase A: h2 compute (L2-hot Wc) + staging into wave-private X ----
        #pragma unroll
        for (int r = 0; r < 16; ++r) {
            const int nr  = __builtin_amdgcn_readlane(nnv, r);         // SGPR
            const int d1r = __builtin_amdgcn_readlane(d1v, r);
            const int d2r = __builtin_amdgcn_readlane(d2v, r);
            const int tyr = (nr >= 2 * per_type) ? 2 : (nr >= per_type ? 1 : 0);
            const float* wcb = Wc + (size_t)tyr * 12800;
            const float h2 = leakyf(wcb[d1r * 64 + lane] + wcb[(100 + d2r) * 64 + lane]
                                    + sBC[tyr * 64 + lane]);
            const int swr = (r & 7) << 4;
            *(_Float16*)(sXw + ((r * 256 + lane * 2) ^ swr))       = (_Float16)fvr[r];
            *(_Float16*)(sXw + ((r * 256 + 128 + lane * 2) ^ swr)) = (_Float16)h2;
        }

        // ---- A-frags for h1 from X[.., 0..63] (consumed before overwrite) ----
        const int swl = (l15 & 7) << 4;
        const half8 a0 = *(const half8*)(sXw + ((l15 * 256 + lq * 16) ^ swl));
        const half8 a1 = *(const half8*)(sXw + ((l15 * 256 + 64 + lq * 16) ^ swl));
        const half8 z8 = {(_Float16)0.f, (_Float16)0.f, (_Float16)0.f, (_Float16)0.f,
                          (_Float16)0.f, (_Float16)0.f, (_Float16)0.f, (_Float16)0.f};
        const int k0 = 2 * tyv, k1 = 2 * tyv + 1;     // live k-slices (per-lane)

        int tyr4[4];
        #pragma unroll
        for (int r = 0; r < 4; ++r) tyr4[r] = __shfl(tyv, (lq << 2) + r);

        // ---- h1 = leaky(F~ @ Wstacked + b[ty_row]) : 24 MFMA -> X[.., 0..63] ----
        #pragma unroll
        for (int n = 0; n < 4; ++n) {
            f32x4 acc = {0.f, 0.f, 0.f, 0.f};
            #pragma unroll
            for (int ks = 0; ks < 6; ++ks) {
                const half8 av = (ks == k0) ? a0 : ((ks == k1) ? a1 : z8);
                const half8 wb = *(const half8*)(sWF + ((ks * 4 + n) << 9) + lane * 8);
                acc = __builtin_amdgcn_mfma_f32_16x16x32_f16(av, wb, acc, 0, 0, 0);
            }
            #pragma unroll
            for (int r = 0; r < 4; ++r) {
                const int row = (lq << 2) + r;                // C/D: row=(lane>>4)*4+reg
                const float v = leakyf(acc[r] + sB[tyr4[r] * 64 + n * 16 + l15]);
                const int off = (row * 256 + (n * 16 + l15) * 2) ^ ((row & 7) << 4);
                *(_Float16*)(sXw + off) = (_Float16)v;        // RNE, matches astype(f16)
            }
        }

        // ---- logits = X @ Wout + bout : 16 MFMA ----
        half8 xa[4];
        #pragma unroll
        for (int ks = 0; ks < 4; ++ks)
            xa[ks] = *(const half8*)(sXw + ((l15 * 256 + ks * 64 + lq * 16) ^ swl));

        #pragma unroll
        for (int n = 0; n < 4; ++n) {
            const float bo = (float)(_Float16)sBout[n * 16 + l15];
            f32x4 acc = {bo, bo, bo, bo};
            #pragma unroll
            for (int ks = 0; ks < 4; ++ks) {
                const half8 wf = *(const half8*)(sOF + ((ks * 4 + n) << 9) + lane * 8);
                acc = __builtin_amdgcn_mfma_f32_16x16x32_f16(xa[ks], wf, acc, 0, 0, 0);
            }
            #pragma unroll
            for (int r = 0; r < 4; ++r) {
                int trr = tile * 16 + (lq << 2) + r;
                if (trr >= T) trr = T - 1;
                out_logits[(size_t)trr * 64 + n * 16 + l15] = (float)(_Float16)acc[r];
            }
        }

        // ---- out_h: per-row streaming fp32 store (rows consecutive) ----
        #pragma unroll
        for (int r = 0; r < 16; ++r) {
            int tb = tile * 16 + r;
            if (tb >= T) tb = T - 1;
            const half2v hv = *(const half2v*)(sXw + ((r * 256 + lane * 4) ^ ((r & 7) << 4)));
            f32x2 o = {(float)hv.x, (float)hv.y};
            *(f32x2*)(out_h + (size_t)tb * 128 + lane * 2) = o;
        }
    }
}

extern "C" void kernel_launch(void* const* d_in, const int* in_sizes, int n_in,
                              void* d_out, int out_size, void* d_ws, size_t ws_size,
                              hipStream_t stream) {
    const float* f0   = (const float*)d_in[0];
    const float* f1   = (const float*)d_in[1];
    const float* f2   = (const float*)d_in[2];
    const float* W    = (const float*)d_in[3];
    const float* b    = (const float*)d_in[4];
    const float* Wc   = (const float*)d_in[5];
    const float* bc   = (const float*)d_in[6];
    const float* Wout = (const float*)d_in[7];
    const float* bout = (const float*)d_in[8];
    const int* deg1   = (const int*)d_in[10];
    const int* deg2   = (const int*)d_in[11];
    const int* tgt    = (const int*)d_in[12];

    const int T = in_sizes[12];
    const int per_type = in_sizes[0] / 64;

    float* out_logits = (float*)d_out;
    float* out_h = out_logits + (size_t)T * 64;

    const int ntiles = (T + 15) / 16;
    int blocks = 512;                    // 2 blocks/CU exactly -> balanced
    if (ntiles < blocks) blocks = ntiles;

    shgnn_fused6<<<dim3(blocks), dim3(512), 0, stream>>>(
        f0, f1, f2, W, b, Wc, bc, Wout, bout,
        tgt, deg1, deg2, T, per_type, out_logits, out_h);
}

// Round 13
// 21.065 us; speedup vs baseline: 1.1432x; 1.1432x over previous
//
#include <hip/hip_runtime.h>
#include <hip/hip_fp16.h>

typedef _Float16 half8 __attribute__((ext_vector_type(8)));
typedef _Float16 half2v __attribute__((ext_vector_type(2)));
typedef float f32x2 __attribute__((ext_vector_type(2)));
typedef float f32x4 __attribute__((ext_vector_type(4)));

__device__ __forceinline__ float leakyf(float v) { return v >= 0.f ? v : 0.7f * v; }

// R11 structure exactly, plus ONE change: hoist ONLY the first tile's tgt row
// and deg1/deg2 per-lane gathers (3 VGPRs) above the weight-staging phase, so
// their two serial HBM round-trips overlap staging. (R12 hoisted the 16 f-row
// loads too -> +16 live VGPRs across staging -> occupancy/spill regression.)
__global__ __launch_bounds__(512, 4)
void shgnn_fused7(const float* __restrict__ f0, const float* __restrict__ f1,
                  const float* __restrict__ f2, const float* __restrict__ W,
                  const float* __restrict__ b, const float* __restrict__ Wc,
                  const float* __restrict__ bc, const float* __restrict__ Wout,
                  const float* __restrict__ bout,
                  const int* __restrict__ tgt, const int* __restrict__ deg1,
                  const int* __restrict__ deg2,
                  int T, int per_type,
                  float* __restrict__ out_logits, float* __restrict__ out_h)
{
    __shared__ _Float16 sWF[24 * 512];   // 24KB: stacked-W B-frags [ks=0..5][n=0..3]
    __shared__ _Float16 sOF[16 * 512];   // 16KB: Wout B-frags [ks=0..3][n=0..3]
    __shared__ _Float16 sX[8][2048];     // 32KB: per-wave [row=16][ch=128] swizzled
    __shared__ float sB[192];
    __shared__ float sBC[192];
    __shared__ float sBout[64];

    const int tid = threadIdx.x;
    const int lane = tid & 63;
    const int l15 = lane & 15;
    const int lq  = lane >> 4;
    const int wid = tid >> 6;
    char* const sXw = (char*)sX[wid];

    const int ntiles = (T + 15) >> 4;

    // balanced contiguous chunk per block
    const int nb = gridDim.x;
    const int q = ntiles / nb, rr = ntiles % nb;
    const int cstart = blockIdx.x * q + (blockIdx.x < rr ? blockIdx.x : rr);
    const int cend   = cstart + q + (blockIdx.x < rr ? 1 : 0);
    const int tile0  = cstart + wid;

    // ---- hoisted first-tile id + deg loads (3 VGPRs; overlap staging) ----
    int nnv = 0, d1v = 0, d2v = 0;
    if (tile0 < cend) {
        int t = tile0 * 16 + l15;
        if (t >= T) t = T - 1;
        nnv = tgt[t];                                 // coalesced 64B
        d1v = deg1[nnv];                              // per-lane gathers
        d2v = deg2[nnv];
    }

    // ---- stage weight fragments (coalesced fp32 reads, scattered b16 writes) ----
    for (int i = tid; i < 3 * 64 * 64; i += 512) {         // i = K*64 + col, K=ty*64+k
        const int K = i >> 6, col = i & 63;
        const int ks = K >> 5, j = K & 7;
        const int ln = (((K >> 3) & 3) << 4) | (col & 15);
        const int n = col >> 4;
        sWF[((ks * 4 + n) << 9) + (ln << 3) + j] = (_Float16)W[i];
    }
    for (int i = tid; i < 128 * 64; i += 512) {            // i = k*64 + col
        const int k = i >> 6, col = i & 63;
        const int ks = k >> 5, j = k & 7;
        const int ln = (((k >> 3) & 3) << 4) | (col & 15);
        const int n = col >> 4;
        sOF[((ks * 4 + n) << 9) + (ln << 3) + j] = (_Float16)Wout[i];
    }
    if (tid < 192) sB[tid] = b[tid];
    if (tid < 192) sBC[tid] = bc[tid];
    if (tid < 64)  sBout[tid] = bout[tid];
    __syncthreads();

    for (int tile = tile0; tile < cend; tile += 8) {
        if (tile != tile0) {                          // cold path (unused at T=50000)
            int t = tile * 16 + l15;
            if (t >= T) t = T - 1;
            nnv = tgt[t];
            d1v = deg1[nnv];
            d2v = deg2[nnv];
        }
        const int tyv = (nnv >= 2 * per_type) ? 2 : (nnv >= per_type ? 1 : 0);

        // ---- phase A: per-row coalesced staging (lane = channel) ----
        #pragma unroll
        for (int r = 0; r < 16; ++r) {
            const int nr  = __builtin_amdgcn_readlane(nnv, r);         // SGPR
            const int d1r = __builtin_amdgcn_readlane(d1v, r);
            const int d2r = __builtin_amdgcn_readlane(d2v, r);
            const int tyr = (nr >= 2 * per_type) ? 2 : (nr >= per_type ? 1 : 0);
            const float* fbr = (tyr == 0) ? f0 : ((tyr == 1) ? f1 : f2);
            const float fv = fbr[(size_t)(nr - tyr * per_type) * 64 + lane];
            const float* wcb = Wc + (size_t)tyr * 12800;
            const float h2 = leakyf(wcb[d1r * 64 + lane] + wcb[(100 + d2r) * 64 + lane]
                                    + sBC[tyr * 64 + lane]);
            const int swr = (r & 7) << 4;
            *(_Float16*)(sXw + ((r * 256 + lane * 2) ^ swr))       = (_Float16)fv;
            *(_Float16*)(sXw + ((r * 256 + 128 + lane * 2) ^ swr)) = (_Float16)h2;
        }

        // ---- A-frags for h1 from X[.., 0..63] (consumed before overwrite) ----
        const int swl = (l15 & 7) << 4;
        const half8 a0 = *(const half8*)(sXw + ((l15 * 256 + lq * 16) ^ swl));
        const half8 a1 = *(const half8*)(sXw + ((l15 * 256 + 64 + lq * 16) ^ swl));
        const half8 z8 = {(_Float16)0.f, (_Float16)0.f, (_Float16)0.f, (_Float16)0.f,
                          (_Float16)0.f, (_Float16)0.f, (_Float16)0.f, (_Float16)0.f};
        const int k0 = 2 * tyv, k1 = 2 * tyv + 1;     // live k-slices (per-lane)

        int tyr4[4];
        #pragma unroll
        for (int r = 0; r < 4; ++r) tyr4[r] = __shfl(tyv, (lq << 2) + r);

        // ---- h1 = leaky(F~ @ Wstacked + b[ty_row]) : 24 MFMA -> X[.., 0..63] ----
        #pragma unroll
        for (int n = 0; n < 4; ++n) {
            f32x4 acc = {0.f, 0.f, 0.f, 0.f};
            #pragma unroll
            for (int ks = 0; ks < 6; ++ks) {
                const half8 av = (ks == k0) ? a0 : ((ks == k1) ? a1 : z8);
                const half8 wb = *(const half8*)(sWF + ((ks * 4 + n) << 9) + lane * 8);
                acc = __builtin_amdgcn_mfma_f32_16x16x32_f16(av, wb, acc, 0, 0, 0);
            }
            #pragma unroll
            for (int r = 0; r < 4; ++r) {
                const int row = (lq << 2) + r;                // C/D: row=(lane>>4)*4+reg
                const float v = leakyf(acc[r] + sB[tyr4[r] * 64 + n * 16 + l15]);
                const int off = (row * 256 + (n * 16 + l15) * 2) ^ ((row & 7) << 4);
                *(_Float16*)(sXw + off) = (_Float16)v;        // RNE, matches astype(f16)
            }
        }

        // ---- logits = X @ Wout + bout : 16 MFMA ----
        half8 xa[4];
        #pragma unroll
        for (int ks = 0; ks < 4; ++ks)
            xa[ks] = *(const half8*)(sXw + ((l15 * 256 + ks * 64 + lq * 16) ^ swl));

        #pragma unroll
        for (int n = 0; n < 4; ++n) {
            const float bo = (float)(_Float16)sBout[n * 16 + l15];
            f32x4 acc = {bo, bo, bo, bo};
            #pragma unroll
            for (int ks = 0; ks < 4; ++ks) {
                const half8 wf = *(const half8*)(sOF + ((ks * 4 + n) << 9) + lane * 8);
                acc = __builtin_amdgcn_mfma_f32_16x16x32_f16(xa[ks], wf, acc, 0, 0, 0);
            }
            #pragma unroll
            for (int r = 0; r < 4; ++r) {
                int trr = tile * 16 + (lq << 2) + r;
                if (trr >= T) trr = T - 1;
                out_logits[(size_t)trr * 64 + n * 16 + l15] = (float)(_Float16)acc[r];
            }
        }

        // ---- out_h: per-row streaming fp32 store (rows consecutive) ----
        #pragma unroll
        for (int r = 0; r < 16; ++r) {
            int tb = tile * 16 + r;
            if (tb >= T) tb = T - 1;
            const half2v hv = *(const half2v*)(sXw + ((r * 256 + lane * 4) ^ ((r & 7) << 4)));
            f32x2 o = {(float)hv.x, (float)hv.y};
            *(f32x2*)(out_h + (size_t)tb * 128 + lane * 2) = o;
        }
    }
}

extern "C" void kernel_launch(void* const* d_in, const int* in_sizes, int n_in,
                              void* d_out, int out_size, void* d_ws, size_t ws_size,
                              hipStream_t stream) {
    const float* f0   = (const float*)d_in[0];
    const float* f1   = (const float*)d_in[1];
    const float* f2   = (const float*)d_in[2];
    const float* W    = (const float*)d_in[3];
    const float* b    = (const float*)d_in[4];
    const float* Wc   = (const float*)d_in[5];
    const float* bc   = (const float*)d_in[6];
    const float* Wout = (const float*)d_in[7];
    const float* bout = (const float*)d_in[8];
    const int* deg1   = (const int*)d_in[10];
    const int* deg2   = (const int*)d_in[11];
    const int* tgt    = (const int*)d_in[12];

    const int T = in_sizes[12];
    const int per_type = in_sizes[0] / 64;

    float* out_logits = (float*)d_out;
    float* out_h = out_logits + (size_t)T * 64;

    const int ntiles = (T + 15) / 16;
    int blocks = 512;                    // 2 blocks/CU exactly -> balanced
    if (ntiles < blocks) blocks = ntiles;

    shgnn_fused7<<<dim3(blocks), dim3(512), 0, stream>>>(
        f0, f1, f2, W, b, Wc, bc, Wout, bout,
        tgt, deg1, deg2, T, per_type, out_logits, out_h);
}